// Round 1
// baseline (38885.883 us; speedup 1.0000x reference)
//
#include <hip/hip_runtime.h>
#include <hip/hip_bf16.h>
#include <stdint.h>

// LSTM scan, persistent-kernel fused design.
// T=2048 steps, B=64, DIN=512, H=512, 4H=2048 gate cols.
// 64 WGs x 256 threads. WG w owns h-cols [8w,8w+8) -> 32 gate cols.
// Waves 0,1: x-half of K (Wx), waves 2,3: h-half (Wh). Weights live in regs
// as MFMA B-frags (64 VGPR/wave). One device-scope barrier per step,
// double-buffered bf16 h in scratch.

#define TSTEPS 2048
#define BATCH  64
#define DINK   512
#define HHH    512
#define GW     64
#define NTHR   256

typedef __attribute__((ext_vector_type(8))) short  short8;
typedef __attribute__((ext_vector_type(4))) float  float4v;

static __device__ __forceinline__ unsigned short f2bf(float f) {
    union { float f; unsigned u; } v; v.f = f;
    unsigned u = v.u + 0x7FFFu + ((v.u >> 16) & 1u);   // RNE
    return (unsigned short)(u >> 16);
}
static __device__ __forceinline__ float sigm(float x) {
    return 1.0f / (1.0f + __expf(-x));
}
static __device__ __forceinline__ float tanh_fast(float x) {
    return 2.0f / (1.0f + __expf(-2.0f * x)) - 1.0f;
}

__global__ __launch_bounds__(NTHR, 1) void lstm_scan(
    const float* __restrict__ X,   // [T][64][512]
    const float* __restrict__ Wx,  // [512][2048]
    const float* __restrict__ bx,  // [2048]
    const float* __restrict__ Wh,  // [512][2048]
    const float* __restrict__ bh,  // [2048]
    float* out,                    // [2][64][512]  (h_sum/T, c_sum/T)
    unsigned short* hbuf,          // 2 x [64][512] bf16 (zeroed)
    unsigned* cnt)                 // barrier counter (zeroed)
{
    __shared__ float P[4][BATCH][33];   // per-wave K-partials, padded
    __shared__ float cst[8][BATCH];     // c state, [jj][b]
    __shared__ float hsum[8][BATCH];
    __shared__ float csum[8][BATCH];
    __shared__ float biasLds[32];

    const int tid  = threadIdx.x;
    const int wv   = tid >> 6;          // wave 0..3
    const int lane = tid & 63;
    const int l15  = lane & 15;
    const int quad = lane >> 4;
    const int w    = blockIdx.x;        // 0..63
    const int jbase = w * 8;

    // ---- preload B fragments (weights, bf16) into registers ----
    // wave0: Wx k[0,256)  wave1: Wx k[256,512)  wave2: Wh k[0,256)  wave3: Wh k[256,512)
    const float* Wsrc = (wv < 2) ? Wx : Wh;
    const int k0 = (wv & 1) * 256;
    short8 bfrag[8][2];
    for (int kc = 0; kc < 8; ++kc) {
        for (int nt = 0; nt < 2; ++nt) {
            int n0   = nt * 16 + l15;                    // 0..31
            int gcol = (n0 >> 3) * 512 + jbase + (n0 & 7);
            int kl   = k0 + kc * 32 + quad * 8;
            short8 tmp;
            #pragma unroll
            for (int j = 0; j < 8; ++j)
                tmp[j] = (short)f2bf(Wsrc[(size_t)(kl + j) * 2048 + gcol]);
            bfrag[kc][nt] = tmp;
        }
    }
    if (tid < 32) {
        int gcol = (tid >> 3) * 512 + jbase + (tid & 7);
        biasLds[tid] = bx[gcol] + bh[gcol];
    }
    for (int i = tid; i < 8 * BATCH; i += NTHR) {
        (&cst[0][0])[i] = 0.f; (&hsum[0][0])[i] = 0.f; (&csum[0][0])[i] = 0.f;
    }
    __syncthreads();

    const int b_ew = tid & 63;     // elementwise: batch row
    const int jj0  = tid >> 6;     // elementwise: jj and jj+4

    for (int t = 0; t < TSTEPS; ++t) {
        const unsigned short* hR = hbuf + ((t + 1) & 1) * (BATCH * HHH);
        unsigned short*       hW = hbuf + (t & 1)       * (BATCH * HHH);

        float4v acc[4][2];
        #pragma unroll
        for (int mt = 0; mt < 4; ++mt)
            #pragma unroll
            for (int nt = 0; nt < 2; ++nt)
                acc[mt][nt] = (float4v){0.f, 0.f, 0.f, 0.f};

        if (wv < 2) {
            // x waves: no dependency on barrier -- overlap with spin of waves 2,3
            const float* xbase = X + (size_t)t * (BATCH * DINK);
            #pragma unroll
            for (int kc = 0; kc < 8; ++kc) {
                const int kg = k0 + kc * 32 + quad * 8;
                short8 a[4];
                #pragma unroll
                for (int mt = 0; mt < 4; ++mt) {
                    const int row = mt * 16 + l15;
                    const float4v* p = (const float4v*)(xbase + (size_t)row * DINK + kg);
                    float4v x0 = p[0], x1 = p[1];
                    short8 av;
                    av[0] = (short)f2bf(x0[0]); av[1] = (short)f2bf(x0[1]);
                    av[2] = (short)f2bf(x0[2]); av[3] = (short)f2bf(x0[3]);
                    av[4] = (short)f2bf(x1[0]); av[5] = (short)f2bf(x1[1]);
                    av[6] = (short)f2bf(x1[2]); av[7] = (short)f2bf(x1[3]);
                    a[mt] = av;
                }
                #pragma unroll
                for (int mt = 0; mt < 4; ++mt)
                    #pragma unroll
                    for (int nt = 0; nt < 2; ++nt)
                        acc[mt][nt] = __builtin_amdgcn_mfma_f32_16x16x32_bf16(
                            a[mt], bfrag[kc][nt], acc[mt][nt], 0, 0, 0);
            }
        } else {
            // h waves: wait for all WGs to publish h_{t-1}
            if (t > 0) {
                const unsigned target = (unsigned)GW * (unsigned)t;
                while (__hip_atomic_load(cnt, __ATOMIC_RELAXED, __HIP_MEMORY_SCOPE_AGENT) < target)
                    __builtin_amdgcn_s_sleep(1);
                __threadfence();   // acquire: invalidate so we see fresh h from other XCDs
            }
            const int hc0 = (wv - 2) * 256;
            #pragma unroll
            for (int kc = 0; kc < 8; ++kc) {
                const int hc = hc0 + kc * 32 + quad * 8;
                short8 a[4];
                #pragma unroll
                for (int mt = 0; mt < 4; ++mt) {
                    const int row = mt * 16 + l15;
                    a[mt] = *(const short8*)(hR + (size_t)row * HHH + hc);
                }
                #pragma unroll
                for (int mt = 0; mt < 4; ++mt)
                    #pragma unroll
                    for (int nt = 0; nt < 2; ++nt)
                        acc[mt][nt] = __builtin_amdgcn_mfma_f32_16x16x32_bf16(
                            a[mt], bfrag[kc][nt], acc[mt][nt], 0, 0, 0);
            }
        }

        // write K-partials to LDS (C layout: row=(quad*4+r)+16*mt, col=l15+16*nt)
        #pragma unroll
        for (int mt = 0; mt < 4; ++mt)
            #pragma unroll
            for (int nt = 0; nt < 2; ++nt) {
                const int row0 = mt * 16 + quad * 4;
                const int col  = nt * 16 + l15;
                #pragma unroll
                for (int r = 0; r < 4; ++r)
                    P[wv][row0 + r][col] = acc[mt][nt][r];
            }
        __syncthreads();

        // elementwise: thread handles (b_ew, jj0) and (b_ew, jj0+4)
        #pragma unroll
        for (int e = 0; e < 2; ++e) {
            const int jj = jj0 + e * 4;
            const int b  = b_ew;
            float gi = biasLds[jj]      + P[0][b][jj]      + P[1][b][jj]      + P[2][b][jj]      + P[3][b][jj];
            float gf = biasLds[8 + jj]  + P[0][b][8 + jj]  + P[1][b][8 + jj]  + P[2][b][8 + jj]  + P[3][b][8 + jj];
            float go = biasLds[16 + jj] + P[0][b][16 + jj] + P[1][b][16 + jj] + P[2][b][16 + jj] + P[3][b][16 + jj];
            float gz = biasLds[24 + jj] + P[0][b][24 + jj] + P[1][b][24 + jj] + P[2][b][24 + jj] + P[3][b][24 + jj];
            const float c_old = cst[jj][b];
            const float cn = sigm(gi) * tanh_fast(gz) + sigm(gf) * c_old;
            const float hn = sigm(go) * tanh_fast(cn);
            cst[jj][b]  = cn;
            csum[jj][b] += cn;
            hsum[jj][b] += hn;
            hW[(size_t)b * HHH + jbase + jj] = f2bf(hn);
        }
        __threadfence();            // release: push h_t to LLC (cross-XCD visibility)
        __syncthreads();
        if (tid == 0)
            __hip_atomic_fetch_add(cnt, 1u, __ATOMIC_RELEASE, __HIP_MEMORY_SCOPE_AGENT);
    }

    // final barrier: nobody may still be reading hbuf when outputs (possibly
    // aliasing scratch in the d_out fallback) are written. Unsigned compare:
    // a clobbered counter can only happen after the target was reached.
    {
        const unsigned target = (unsigned)(GW * TSTEPS);
        while (__hip_atomic_load(cnt, __ATOMIC_RELAXED, __HIP_MEMORY_SCOPE_AGENT) < target)
            __builtin_amdgcn_s_sleep(1);
    }
    const float invT = 1.0f / (float)TSTEPS;
    #pragma unroll
    for (int e = 0; e < 2; ++e) {
        const int jj = jj0 + e * 4;
        const int b  = b_ew;
        out[(size_t)b * HHH + jbase + jj]                       = hsum[jj][b] * invT;
        out[(size_t)(BATCH * HHH) + (size_t)b * HHH + jbase + jj] = csum[jj][b] * invT;
    }
}

extern "C" void kernel_launch(void* const* d_in, const int* in_sizes, int n_in,
                              void* d_out, int out_size, void* d_ws, size_t ws_size,
                              hipStream_t stream) {
    (void)in_sizes; (void)n_in; (void)out_size;
    const float* X  = (const float*)d_in[0];
    const float* Wx = (const float*)d_in[1];
    const float* bx = (const float*)d_in[2];
    const float* Wh = (const float*)d_in[3];
    const float* bh = (const float*)d_in[4];
    float* out = (float*)d_out;

    const size_t HBUF_BYTES = (size_t)2 * BATCH * HHH * 2;   // 128 KiB
    char* scratch = (ws_size >= HBUF_BYTES + 64) ? (char*)d_ws : (char*)d_out;
    unsigned short* hbuf = (unsigned short*)scratch;
    unsigned* cnt = (unsigned*)(scratch + HBUF_BYTES);

    hipMemsetAsync(scratch, 0, HBUF_BYTES + 64, stream);
    lstm_scan<<<GW, NTHR, 0, stream>>>(X, Wx, bx, Wh, bh, out, hbuf, cnt);
}

// Round 3
// 14083.138 us; speedup vs baseline: 2.7612x; 2.7612x over previous
//
#include <hip/hip_runtime.h>
#include <hip/hip_bf16.h>
#include <stdint.h>

// LSTM scan R3: LLC-direct handoff + row-group partitioning.
// T=2048, B=64, DIN=H=512. Grid = 4 row-groups x 16 col-WGs = 64 WGs x 256 thr.
// Group g owns batch rows [16g,16g+16) -- the recurrence is row-independent,
// so each group runs its own 2048-step scan with a PRIVATE 16-participant
// barrier (R2 had one 64-participant barrier).
// WG (g,wc) owns h-cols [32wc,32wc+32) -> 128 gate cols; weights live in
// registers as MFMA B-frags (8kc x 8nt short8 = 256 VGPR/thread).
// Waves 0,1: Wx K-halves (no barrier dep); waves 2,3: Wh K-halves.
//
// Coherence protocol (no wbl2/buffer_inv anywhere -- R2's post-timing race
// was traced to relying on those walks):
//   h stores: packed 2xbf16 agent-scope RELAXED atomic dword stores (sc1 ->
//             complete at LLC; __syncthreads vmcnt(0) drains them).
//   arrive:   tid0 RELAXED fetch_add; 16th arriver RELAXED-stores epoch flag.
//   h loads:  agent-scope RELAXED atomic dwordx2 (sc1 -> always LLC-fresh).
//   poll:     read-only relaxed on flag line + s_sleep backoff; workgroup
//             acquire fence after (compile-order only, no cache ops).

#define TSTEPS 2048
#define BATCH  64
#define DINK   512
#define HHH    512
#define GB     4
#define GC     16
#define ROWS   16
#define NTHR   256

typedef __attribute__((ext_vector_type(8))) short  short8;
typedef __attribute__((ext_vector_type(4))) float  float4v;

static __device__ __forceinline__ unsigned short f2bf(float f) {
    union { float f; unsigned u; } v; v.f = f;
    unsigned u = v.u + 0x7FFFu + ((v.u >> 16) & 1u);   // RNE
    return (unsigned short)(u >> 16);
}
static __device__ __forceinline__ float sigm(float x) {
    return 1.0f / (1.0f + __expf(-x));
}
static __device__ __forceinline__ float tanh_fast(float x) {
    return 2.0f / (1.0f + __expf(-2.0f * x)) - 1.0f;
}

__global__ __launch_bounds__(NTHR, 1) void lstm_scan(
    const float* __restrict__ X,   // [T][64][512]
    const float* __restrict__ Wx,  // [512][2048]
    const float* __restrict__ bx,  // [2048]
    const float* __restrict__ Wh,  // [512][2048]
    const float* __restrict__ bh,  // [2048]
    float* out,                    // [2][64][512]
    unsigned short* hbuf,          // 2 x [64][512] bf16 (zeroed)
    unsigned* sync)                // per group: [g*256]=flag, [g*256+64]=arrive
{
    __shared__ float P[4][ROWS][132];   // per-wave K-partials (stride 132: 2-way max on writes)
    __shared__ float cst[ROWS][33];
    __shared__ float hsum[ROWS][33];
    __shared__ float csum[ROWS][33];
    __shared__ float biasLds[128];

    const int tid  = threadIdx.x;
    const int wv   = tid >> 6;
    const int lane = tid & 63;
    const int l15  = lane & 15;
    const int quad = lane >> 4;
    const int g    = blockIdx.x >> 4;   // row group 0..3
    const int wc   = blockIdx.x & 15;   // col-WG 0..15
    const int rb   = g * ROWS;          // first batch row of group
    const int jbase = wc * 32;          // first h-col of WG

    unsigned* flagp   = sync + g * 256;
    unsigned* arrivep = sync + g * 256 + 64;

    // ---- preload B fragments (weights, bf16) into registers ----
    const float* Wsrc = (wv < 2) ? Wx : Wh;
    const int k0 = (wv & 1) * 256;
    short8 bfrag[8][8];
    #pragma unroll
    for (int kc = 0; kc < 8; ++kc) {
        #pragma unroll
        for (int nt = 0; nt < 8; ++nt) {
            const int c    = nt * 16 + l15;                  // 0..127
            const int gcol = (c >> 5) * HHH + jbase + (c & 31);
            const int kl   = k0 + kc * 32 + quad * 8;
            short8 tmp;
            #pragma unroll
            for (int j = 0; j < 8; ++j)
                tmp[j] = (short)f2bf(Wsrc[(size_t)(kl + j) * 2048 + gcol]);
            bfrag[kc][nt] = tmp;
        }
    }
    if (tid < 128) {
        const int gcol = (tid >> 5) * HHH + jbase + (tid & 31);
        biasLds[tid] = bx[gcol] + bh[gcol];
    }
    for (int i = tid; i < ROWS * 33; i += NTHR) {
        (&cst[0][0])[i] = 0.f; (&hsum[0][0])[i] = 0.f; (&csum[0][0])[i] = 0.f;
    }
    __syncthreads();

    const int r_ew  = tid >> 4;          // 0..15 (row in group)
    const int jj_ew = (tid & 15) * 2;    // 0,2,..,30 (adjacent pair of h-cols)

    for (int t = 0; t < TSTEPS; ++t) {
        const unsigned short* hR = hbuf + ((t + 1) & 1) * (BATCH * HHH);
        unsigned short*       hW = hbuf + (t & 1)       * (BATCH * HHH);

        float4v acc[8];
        #pragma unroll
        for (int nt = 0; nt < 8; ++nt) acc[nt] = (float4v){0.f, 0.f, 0.f, 0.f};

        if (wv < 2) {
            // x waves: independent of the barrier; overlap with h-wave wait
            const float* xbase = X + (size_t)t * (BATCH * DINK) + (size_t)(rb + l15) * DINK;
            #pragma unroll
            for (int kc = 0; kc < 8; ++kc) {
                const int kg = k0 + kc * 32 + quad * 8;
                const float4v* p = (const float4v*)(xbase + kg);
                float4v x0 = p[0], x1 = p[1];
                short8 a;
                a[0] = (short)f2bf(x0[0]); a[1] = (short)f2bf(x0[1]);
                a[2] = (short)f2bf(x0[2]); a[3] = (short)f2bf(x0[3]);
                a[4] = (short)f2bf(x1[0]); a[5] = (short)f2bf(x1[1]);
                a[6] = (short)f2bf(x1[2]); a[7] = (short)f2bf(x1[3]);
                #pragma unroll
                for (int nt = 0; nt < 8; ++nt)
                    acc[nt] = __builtin_amdgcn_mfma_f32_16x16x32_bf16(
                        a, bfrag[kc][nt], acc[nt], 0, 0, 0);
            }
        } else {
            if (t > 0) {
                while (__hip_atomic_load(flagp, __ATOMIC_RELAXED, __HIP_MEMORY_SCOPE_AGENT) < (unsigned)t)
                    __builtin_amdgcn_s_sleep(1);
                __builtin_amdgcn_fence(__ATOMIC_ACQUIRE, "workgroup");  // order only; h loads are sc1
            }
            const int hc0 = (wv - 2) * 256;
            #pragma unroll
            for (int kc = 0; kc < 8; ++kc) {
                const int hc = hc0 + kc * 32 + quad * 8;
                const unsigned long long* hp =
                    (const unsigned long long*)(hR + (size_t)(rb + l15) * HHH + hc);
                unsigned long long lo = __hip_atomic_load(hp,     __ATOMIC_RELAXED, __HIP_MEMORY_SCOPE_AGENT);
                unsigned long long hi = __hip_atomic_load(hp + 1, __ATOMIC_RELAXED, __HIP_MEMORY_SCOPE_AGENT);
                union { unsigned long long q[2]; short8 s; } u;
                u.q[0] = lo; u.q[1] = hi;
                #pragma unroll
                for (int nt = 0; nt < 8; ++nt)
                    acc[nt] = __builtin_amdgcn_mfma_f32_16x16x32_bf16(
                        u.s, bfrag[kc][nt], acc[nt], 0, 0, 0);
            }
        }

        // K-partials to LDS (C layout: row = quad*4+r, col = nt*16+l15)
        #pragma unroll
        for (int nt = 0; nt < 8; ++nt) {
            const int col = nt * 16 + l15;
            #pragma unroll
            for (int r = 0; r < 4; ++r)
                P[wv][quad * 4 + r][col] = acc[nt][r];
        }
        __syncthreads();

        // elementwise: thread -> (row r_ew, h-cols jj_ew, jj_ew+1)
        {
            float h2[2];
            #pragma unroll
            for (int e = 0; e < 2; ++e) {
                const int jj = jj_ew + e;
                const int r  = r_ew;
                float gi = biasLds[jj]      + P[0][r][jj]      + P[1][r][jj]      + P[2][r][jj]      + P[3][r][jj];
                float gf = biasLds[32 + jj] + P[0][r][32 + jj] + P[1][r][32 + jj] + P[2][r][32 + jj] + P[3][r][32 + jj];
                float go = biasLds[64 + jj] + P[0][r][64 + jj] + P[1][r][64 + jj] + P[2][r][64 + jj] + P[3][r][64 + jj];
                float gz = biasLds[96 + jj] + P[0][r][96 + jj] + P[1][r][96 + jj] + P[2][r][96 + jj] + P[3][r][96 + jj];
                const float c_old = cst[r][jj];
                const float cn = sigm(gi) * tanh_fast(gz) + sigm(gf) * c_old;
                const float hn = sigm(go) * tanh_fast(cn);
                cst[r][jj]  = cn;
                csum[r][jj] += cn;
                hsum[r][jj] += hn;
                h2[e] = hn;
            }
            const unsigned pk = (unsigned)f2bf(h2[0]) | ((unsigned)f2bf(h2[1]) << 16);
            unsigned* dst = (unsigned*)(hW + (size_t)(rb + r_ew) * HHH + jbase + jj_ew);
            __hip_atomic_store(dst, pk, __ATOMIC_RELAXED, __HIP_MEMORY_SCOPE_AGENT);  // sc1 -> LLC
        }
        __syncthreads();   // vmcnt(0): all sc1 h-stores of this WG are at LLC
        if (tid == 0) {
            unsigned old = __hip_atomic_fetch_add(arrivep, 1u, __ATOMIC_RELAXED,
                                                  __HIP_MEMORY_SCOPE_AGENT);
            if (old == (unsigned)GC * (unsigned)(t + 1) - 1u)
                __hip_atomic_store(flagp, (unsigned)(t + 1), __ATOMIC_RELAXED,
                                   __HIP_MEMORY_SCOPE_AGENT);
        }
    }

    // global final barrier (covers the d_out-fallback aliasing case): wait for
    // ALL groups before any output write. tid0 polls, others wait at barrier.
    if (tid == 0) {
        #pragma unroll
        for (int gg = 0; gg < GB; ++gg)
            while (__hip_atomic_load(sync + gg * 256, __ATOMIC_RELAXED, __HIP_MEMORY_SCOPE_AGENT) < (unsigned)TSTEPS)
                __builtin_amdgcn_s_sleep(1);
    }
    __syncthreads();

    const float invT = 1.0f / (float)TSTEPS;
    {
        const int b = rb + r_ew;
        const size_t o0 = (size_t)b * HHH + jbase + jj_ew;
        out[o0]                          = hsum[r_ew][jj_ew] * invT;
        out[o0 + 1]                      = hsum[r_ew][jj_ew + 1] * invT;
        out[(size_t)(BATCH * HHH) + o0]      = csum[r_ew][jj_ew] * invT;
        out[(size_t)(BATCH * HHH) + o0 + 1]  = csum[r_ew][jj_ew + 1] * invT;
    }
}

extern "C" void kernel_launch(void* const* d_in, const int* in_sizes, int n_in,
                              void* d_out, int out_size, void* d_ws, size_t ws_size,
                              hipStream_t stream) {
    (void)in_sizes; (void)n_in; (void)out_size;
    const float* X  = (const float*)d_in[0];
    const float* Wx = (const float*)d_in[1];
    const float* bx = (const float*)d_in[2];
    const float* Wh = (const float*)d_in[3];
    const float* bh = (const float*)d_in[4];
    float* out = (float*)d_out;

    const size_t HBUF_BYTES = (size_t)2 * BATCH * HHH * 2;   // 128 KiB
    const size_t SYNC_BYTES = 4096;                          // 4 groups x 1 KiB
    char* scratch = (ws_size >= HBUF_BYTES + SYNC_BYTES) ? (char*)d_ws : (char*)d_out;
    unsigned short* hbuf = (unsigned short*)scratch;
    unsigned* sync = (unsigned*)(scratch + HBUF_BYTES);

    hipMemsetAsync(scratch, 0, HBUF_BYTES + SYNC_BYTES, stream);
    lstm_scan<<<GB * GC, NTHR, 0, stream>>>(X, Wx, bx, Wh, bh, out, hbuf, sync);
}